// Round 7
// baseline (713.184 us; speedup 1.0000x reference)
//
#include <hip/hip_runtime.h>
#include <hip/hip_bf16.h>
#include <math.h>

#define NAB 128
#define NG 50
#define TK 1024      // ef interpolation grid points
#define BN 128       // nodes per bucket
#define CAP 8704     // slot capacity per bucket (mean 8192, sigma ~90 -> +5.7 sigma)
#define CPAD 16      // ints per bucket cursor (own 64B line)
#define SKEY 16      // secondary key: coarse src region (src>>12; 0..12 for N=50000)

__device__ __forceinline__ float sspf(float x) {
  float t = __expf(-fabsf(x));
  return fmaxf(x, 0.0f) + __logf(1.0f + t) - 0.69314718055994531f;
}

// ---------------------------------------------------------------------------
// C[M,128] = A[M,128] @ W[128,128] (+ bias) (optional ssp epilogue)
__global__ __launch_bounds__(128)
void gemm128(const float* __restrict__ A, const float* __restrict__ W,
             const float* __restrict__ bias, float* __restrict__ C,
             int M, int do_ssp) {
  __shared__ float Wl[128 * 128];
  __shared__ float Al[32 * 128];
  const int tid = threadIdx.x;
  const int r0 = blockIdx.x * 32;
  const int rows = min(32, M - r0);

  {
    const float4* W4 = (const float4*)W;
    float4* Wl4 = (float4*)Wl;
#pragma unroll
    for (int k = 0; k < 32; ++k) Wl4[tid + k * 128] = W4[tid + k * 128];
  }
  {
    const float4* A4 = (const float4*)(A + (size_t)r0 * NAB);
    float4* Al4 = (float4*)Al;
    for (int f = tid; f < rows * 32; f += 128) Al4[f] = A4[f];
  }
  __syncthreads();

  const int c = tid & 31;
  const int gq = tid >> 5;
  float acc[8][4];
#pragma unroll
  for (int j = 0; j < 8; ++j) {
    acc[j][0] = 0.f; acc[j][1] = 0.f; acc[j][2] = 0.f; acc[j][3] = 0.f;
  }
  const float4* Wl4 = (const float4*)Wl;
  for (int i = 0; i < 128; i += 4) {
    float4 w0 = Wl4[(i + 0) * 32 + c];
    float4 w1 = Wl4[(i + 1) * 32 + c];
    float4 w2 = Wl4[(i + 2) * 32 + c];
    float4 w3 = Wl4[(i + 3) * 32 + c];
#pragma unroll
    for (int j = 0; j < 8; ++j) {
      float4 av = *(const float4*)&Al[(gq * 8 + j) * 128 + i];
      acc[j][0] += av.x * w0.x + av.y * w1.x + av.z * w2.x + av.w * w3.x;
      acc[j][1] += av.x * w0.y + av.y * w1.y + av.z * w2.y + av.w * w3.y;
      acc[j][2] += av.x * w0.z + av.y * w1.z + av.z * w2.z + av.w * w3.z;
      acc[j][3] += av.x * w0.w + av.y * w1.w + av.z * w2.w + av.w * w3.w;
    }
  }
  float4 bv = make_float4(0.f, 0.f, 0.f, 0.f);
  if (bias) bv = *(const float4*)&bias[4 * c];
#pragma unroll
  for (int j = 0; j < 8; ++j) {
    int row = gq * 8 + j;
    if (row < rows) {
      float4 o;
      o.x = acc[j][0] + bv.x;
      o.y = acc[j][1] + bv.y;
      o.z = acc[j][2] + bv.z;
      o.w = acc[j][3] + bv.w;
      if (do_ssp) { o.x = sspf(o.x); o.y = sspf(o.y); o.z = sspf(o.z); o.w = sspf(o.w); }
      *(float4*)&C[(size_t)(r0 + row) * NAB + 4 * c] = o;
    }
  }
}

// ---------------------------------------------------------------------------
// Build interleaved lerp table directly:
// Tp4[k][l] = (ef(x_k)[2l], ef(x_{k+1})[2l], ef(x_k)[2l+1], ef(x_{k+1})[2l+1])
__global__ __launch_bounds__(128)
void build_tp(const float* __restrict__ W1, const float* __restrict__ b1,
              const float* __restrict__ W2, const float* __restrict__ b2,
              float4* __restrict__ Tp4) {
  __shared__ float h0[NG], h1[NG], e0[NAB], e1[NAB];
  const int k = blockIdx.x;       // 0 .. TK-2
  const int tid = threadIdx.x;
  constexpr float width = 5.0f / 49.0f;
  constexpr float coeff = -0.5f / (width * width);
  const float x0 = (float)k * (5.0f / (float)(TK - 1));
  const float x1 = (float)(k + 1) * (5.0f / (float)(TK - 1));

  if (tid < NG) {
    float a0 = b1[tid], a1 = b1[tid];
    for (int i = 0; i < NG; ++i) {
      float w = W1[i * NG + tid];
      float d0 = x0 - i * width;
      float d1 = x1 - i * width;
      a0 = __fmaf_rn(__expf(coeff * d0 * d0), w, a0);
      a1 = __fmaf_rn(__expf(coeff * d1 * d1), w, a1);
    }
    h0[tid] = sspf(a0);
    h1[tid] = sspf(a1);
  }
  __syncthreads();
  float f0 = b2[tid], f1 = b2[tid];
#pragma unroll 10
  for (int i = 0; i < NG; ++i) {
    float w = W2[i * NAB + tid];
    f0 = __fmaf_rn(h0[i], w, f0);
    f1 = __fmaf_rn(h1[i], w, f1);
  }
  e0[tid] = f0;
  e1[tid] = f1;
  __syncthreads();
  if (tid < 64) {
    float4 v;
    v.x = e0[2 * tid]; v.y = e1[2 * tid];
    v.z = e0[2 * tid + 1]; v.w = e1[2 * tid + 1];
    Tp4[(size_t)k * 64 + tid] = v;
  }
}

// ---------------------------------------------------------------------------
// Scatter (src | tl<<16, e_bits) into fixed-capacity bucket slots.
__global__ __launch_bounds__(256)
void bscatter_kernel(const int* __restrict__ a, const float* __restrict__ e,
                     int* __restrict__ bcur, int2* __restrict__ items, int E) {
  int i = blockIdx.x * 256 + threadIdx.x;
  if (i >= 2 * E) return;
  int edge, tgt, src;
  if (i < E) {
    edge = i; src = a[2 * i]; tgt = a[2 * i + 1];
  } else {
    edge = i - E; tgt = a[2 * edge]; src = a[2 * edge + 1];
  }
  int b = tgt >> 7;
  int pos = atomicAdd(&bcur[b * CPAD], 1);
  if (pos < CAP)
    items[(size_t)b * CAP + pos] = make_int2(src | ((tgt & 127) << 16),
                                             __float_as_int(e[edge]));
}

// ---------------------------------------------------------------------------
// Per-bucket counting sort in LDS with key = (node_low7, src>>12).
// Secondary key makes every node's item list ascend through src-space, so
// concurrent pull waves traverse rf in approximate lockstep -> L2-sized
// sliding window instead of 25.6 MB random gather.
__global__ __launch_bounds__(256)
void local_sort(const int* __restrict__ bcur, int2* __restrict__ items,
                int* __restrict__ nstart, int* __restrict__ nend, int N) {
  __shared__ int2 lit[CAP];
  __shared__ int bin[BN * SKEY];
  __shared__ int cur[BN * SKEY];
  __shared__ int sums[256];
  const int b = blockIdx.x;
  const int tid = threadIdx.x;
  const int cnt = min(bcur[b * CPAD], CAP);
  const size_t base = (size_t)b * CAP;

  for (int i = tid; i < cnt; i += 256) lit[i] = items[base + i];
#pragma unroll
  for (int q = 0; q < (BN * SKEY) / 256; ++q) bin[tid + q * 256] = 0;
  __syncthreads();
  for (int i = tid; i < cnt; i += 256) {
    int2 it = lit[i];
    int key = (((it.x >> 16) & 127) << 4) | ((it.x & 0xffff) >> 12);
    atomicAdd(&bin[key], 1);
  }
  __syncthreads();
  // scan 2048 bins: 8 per thread, then block scan of per-thread totals
  const int b8 = tid * 8;
  int loc[8];
  int s = 0;
#pragma unroll
  for (int q = 0; q < 8; ++q) { loc[q] = s; s += bin[b8 + q]; }
  sums[tid] = s;
  __syncthreads();
  for (int d = 1; d < 256; d <<= 1) {
    int v = (tid >= d) ? sums[tid - d] : 0;
    __syncthreads();
    sums[tid] += v;
    __syncthreads();
  }
  int off = (tid == 0) ? 0 : sums[tid - 1];
#pragma unroll
  for (int q = 0; q < 8; ++q) cur[b8 + q] = off + loc[q];
  __syncthreads();
  if (tid < BN) {
    int n = b * BN + tid;
    if (n < N) {
      nstart[n] = (int)base + cur[tid * SKEY];
      nend[n]   = (int)base + ((tid == BN - 1) ? cnt : cur[(tid + 1) * SKEY]);
    }
  }
  __syncthreads();
  for (int i = tid; i < cnt; i += 256) {
    int2 it = lit[i];
    int key = (((it.x >> 16) & 127) << 4) | ((it.x & 0xffff) >> 12);
    int pos = atomicAdd(&cur[key], 1);
    items[base + pos] = it;
  }
}

// ---------------------------------------------------------------------------
// Pull: one WAVE per node, register accumulator (2 features/lane), no atomics.
// 8-deep pipeline: 8 independent item loads hoist ahead of 16 dependent gathers.
__global__ __launch_bounds__(256)
void pull_kernel(const int* __restrict__ nstart, const int* __restrict__ nend,
                 const int2* __restrict__ items, const float* __restrict__ rf,
                 const float4* __restrict__ Tp4, float* __restrict__ agg, int N) {
  const int wv = __builtin_amdgcn_readfirstlane(threadIdx.x >> 6);
  const int n = blockIdx.x * 4 + wv;
  if (n >= N) return;
  const int l = threadIdx.x & 63;
  int j  = nstart[n];
  const int j1 = nend[n];
  const float scale = (float)(TK - 1) / 5.0f;
  float a0 = 0.f, a1 = 0.f;

  for (; j + 8 <= j1; j += 8) {
    int2 p[8];
#pragma unroll
    for (int u = 0; u < 8; ++u) p[u] = items[j + u];
    float4 tv[8];
    float2 rv[8];
    float fr[8];
#pragma unroll
    for (int u = 0; u < 8; ++u) {
      float x = __int_as_float(p[u].y) * scale;
      int k = min((int)x, TK - 2);
      fr[u] = x - (float)k;
      tv[u] = Tp4[(size_t)k * 64 + l];
      rv[u] = *(const float2*)&rf[((size_t)(p[u].x & 0xffff) << 7) + 2 * l];
    }
#pragma unroll
    for (int u = 0; u < 8; ++u) {
      a0 = __fmaf_rn(rv[u].x, __fmaf_rn(fr[u], tv[u].y - tv[u].x, tv[u].x), a0);
      a1 = __fmaf_rn(rv[u].y, __fmaf_rn(fr[u], tv[u].w - tv[u].z, tv[u].z), a1);
    }
  }
  for (; j < j1; ++j) {
    int2 p = items[j];
    float x = __int_as_float(p.y) * scale;
    int k = min((int)x, TK - 2);
    float fr = x - (float)k;
    float4 tv = Tp4[(size_t)k * 64 + l];
    float2 rv = *(const float2*)&rf[((size_t)(p.x & 0xffff) << 7) + 2 * l];
    a0 = __fmaf_rn(rv.x, __fmaf_rn(fr, tv.y - tv.x, tv.x), a0);
    a1 = __fmaf_rn(rv.y, __fmaf_rn(fr, tv.w - tv.z, tv.z), a1);
  }
  float2 o; o.x = a0; o.y = a1;
  *(float2*)&agg[((size_t)n << 7) + 2 * l] = o;
}

// ---------------------------------------------------------------------------
extern "C" void kernel_launch(void* const* d_in, const int* in_sizes, int n_in,
                              void* d_out, int out_size, void* d_ws, size_t ws_size,
                              hipStream_t stream) {
  const float* r     = (const float*)d_in[0];
  const float* e     = (const float*)d_in[1];
  const int*   a     = (const int*)d_in[2];
  const float* W_df1 = (const float*)d_in[3];
  const float* b_df1 = (const float*)d_in[4];
  const float* W_df2 = (const float*)d_in[5];
  const float* b_df2 = (const float*)d_in[6];
  const float* W_af  = (const float*)d_in[7];
  const float* W_d1  = (const float*)d_in[8];
  const float* b_d1  = (const float*)d_in[9];
  const float* W_d2  = (const float*)d_in[10];
  const float* b_d2  = (const float*)d_in[11];

  const int N = in_sizes[0] / NAB;
  const int E = in_sizes[1];
  const int H = 2 * E;
  const int NB = (N + BN - 1) / BN;

  // workspace layout (~80 MB)
  float*  rf     = (float*)d_ws;                          // N*128 floats
  float*  agg    = rf + (size_t)N * NAB;                  // N*128 floats
  float4* Tp4    = (float4*)(agg + (size_t)N * NAB);      // (TK-1)*64 float4
  int2*   items  = (int2*)(Tp4 + (size_t)(TK - 1) * 64);  // NB*CAP int2
  int*    bcur   = (int*)(items + (size_t)NB * CAP);      // NB*CPAD ints
  int*    nstart = bcur + NB * CPAD;                      // NB*BN ints
  int*    nend   = nstart + NB * BN;                      // NB*BN ints
  float*  t1     = rf;                                    // reuse rf after pull

  const int gblocks = (N + 31) / 32;
  const int hblocks = (H + 255) / 256;

  // 1) interleaved ef lerp table
  build_tp<<<TK - 1, 128, 0, stream>>>(W_df1, b_df1, W_df2, b_df2, Tp4);
  // 2) rf = r @ W_af
  gemm128<<<gblocks, 128, 0, stream>>>(r, W_af, nullptr, rf, N, 0);
  // 3) slot-scatter into 128-node buckets
  hipMemsetAsync(bcur, 0, (size_t)NB * CPAD * sizeof(int), stream);
  bscatter_kernel<<<hblocks, 256, 0, stream>>>(a, e, bcur, items, E);
  // 4) per-bucket counting sort by (node, coarse-src) -> CSR + src-ordered items
  local_sort<<<NB, 256, 0, stream>>>(bcur, items, nstart, nend, N);
  // 5) wave-per-node pull, register accumulation, no atomics
  pull_kernel<<<(N + 3) / 4, 256, 0, stream>>>(nstart, nend, items, rf, Tp4, agg, N);
  // 6) t1 = ssp(agg @ W_d1 + b_d1)
  gemm128<<<gblocks, 128, 0, stream>>>(agg, W_d1, b_d1, t1, N, 1);
  // 7) out = t1 @ W_d2 + b_d2
  gemm128<<<gblocks, 128, 0, stream>>>(t1, W_d2, b_d2, (float*)d_out, N, 0);
}

// Round 10
// 639.822 us; speedup vs baseline: 1.1147x; 1.1147x over previous
//
#include <hip/hip_runtime.h>
#include <hip/hip_fp16.h>
#include <math.h>

#define NAB 128
#define NG 50
#define TK 1024      // ef interpolation grid points
#define BN 128       // nodes per bucket
#define CAP 8704     // slot capacity per bucket (max bucket load verified R6/R7)
#define CPAD 16      // ints per bucket cursor (own 64B line)

__device__ __forceinline__ float sspf(float x) {
  float t = __expf(-fabsf(x));
  return fmaxf(x, 0.0f) + __logf(1.0f + t) - 0.69314718055994531f;
}

// ---------------------------------------------------------------------------
// C[M,128] = A[M,128] @ W[128,128] (+ bias) (optional ssp epilogue) — R6 verbatim
__global__ __launch_bounds__(128)
void gemm128(const float* __restrict__ A, const float* __restrict__ W,
             const float* __restrict__ bias, float* __restrict__ C,
             int M, int do_ssp) {
  __shared__ float Wl[128 * 128];
  __shared__ float Al[32 * 128];
  const int tid = threadIdx.x;
  const int r0 = blockIdx.x * 32;
  const int rows = min(32, M - r0);

  {
    const float4* W4 = (const float4*)W;
    float4* Wl4 = (float4*)Wl;
#pragma unroll
    for (int k = 0; k < 32; ++k) Wl4[tid + k * 128] = W4[tid + k * 128];
  }
  {
    const float4* A4 = (const float4*)(A + (size_t)r0 * NAB);
    float4* Al4 = (float4*)Al;
    for (int f = tid; f < rows * 32; f += 128) Al4[f] = A4[f];
  }
  __syncthreads();

  const int c = tid & 31;
  const int gq = tid >> 5;
  float acc[8][4];
#pragma unroll
  for (int j = 0; j < 8; ++j) {
    acc[j][0] = 0.f; acc[j][1] = 0.f; acc[j][2] = 0.f; acc[j][3] = 0.f;
  }
  const float4* Wl4 = (const float4*)Wl;
  for (int i = 0; i < 128; i += 4) {
    float4 w0 = Wl4[(i + 0) * 32 + c];
    float4 w1 = Wl4[(i + 1) * 32 + c];
    float4 w2 = Wl4[(i + 2) * 32 + c];
    float4 w3 = Wl4[(i + 3) * 32 + c];
#pragma unroll
    for (int j = 0; j < 8; ++j) {
      float4 av = *(const float4*)&Al[(gq * 8 + j) * 128 + i];
      acc[j][0] += av.x * w0.x + av.y * w1.x + av.z * w2.x + av.w * w3.x;
      acc[j][1] += av.x * w0.y + av.y * w1.y + av.z * w2.y + av.w * w3.y;
      acc[j][2] += av.x * w0.z + av.y * w1.z + av.z * w2.z + av.w * w3.z;
      acc[j][3] += av.x * w0.w + av.y * w1.w + av.z * w2.w + av.w * w3.w;
    }
  }
  float4 bv = make_float4(0.f, 0.f, 0.f, 0.f);
  if (bias) bv = *(const float4*)&bias[4 * c];
#pragma unroll
  for (int j = 0; j < 8; ++j) {
    int row = gq * 8 + j;
    if (row < rows) {
      float4 o;
      o.x = acc[j][0] + bv.x;
      o.y = acc[j][1] + bv.y;
      o.z = acc[j][2] + bv.z;
      o.w = acc[j][3] + bv.w;
      if (do_ssp) { o.x = sspf(o.x); o.y = sspf(o.y); o.z = sspf(o.z); o.w = sspf(o.w); }
      *(float4*)&C[(size_t)(r0 + row) * NAB + 4 * c] = o;
    }
  }
}

// ---------------------------------------------------------------------------
// rf (fp32) -> rfh (fp16), 4 elements per thread.
__global__ __launch_bounds__(256)
void cast_rf(const float4* __restrict__ rf4, uint2* __restrict__ rfh2, int n4) {
  int i = blockIdx.x * 256 + threadIdx.x;
  if (i >= n4) return;
  float4 v = rf4[i];
  __half2 h01 = __floats2half2_rn(v.x, v.y);
  __half2 h23 = __floats2half2_rn(v.z, v.w);
  uint2 o;
  o.x = *(unsigned*)&h01;
  o.y = *(unsigned*)&h23;
  rfh2[i] = o;
}

// ---------------------------------------------------------------------------
// Build interleaved fp32 lerp table (R6 verbatim):
// Tp4[k][l] = (ef(x_k)[2l], ef(x_{k+1})[2l], ef(x_k)[2l+1], ef(x_{k+1})[2l+1])
__global__ __launch_bounds__(128)
void build_tp(const float* __restrict__ W1, const float* __restrict__ b1,
              const float* __restrict__ W2, const float* __restrict__ b2,
              float4* __restrict__ Tp4) {
  __shared__ float h0[NG], h1[NG], e0[NAB], e1[NAB];
  const int k = blockIdx.x;       // 0 .. TK-2
  const int tid = threadIdx.x;
  constexpr float width = 5.0f / 49.0f;
  constexpr float coeff = -0.5f / (width * width);
  const float x0 = (float)k * (5.0f / (float)(TK - 1));
  const float x1 = (float)(k + 1) * (5.0f / (float)(TK - 1));

  if (tid < NG) {
    float a0 = b1[tid], a1 = b1[tid];
    for (int i = 0; i < NG; ++i) {
      float w = W1[i * NG + tid];
      float d0 = x0 - i * width;
      float d1 = x1 - i * width;
      a0 = __fmaf_rn(__expf(coeff * d0 * d0), w, a0);
      a1 = __fmaf_rn(__expf(coeff * d1 * d1), w, a1);
    }
    h0[tid] = sspf(a0);
    h1[tid] = sspf(a1);
  }
  __syncthreads();
  float f0 = b2[tid], f1 = b2[tid];
#pragma unroll 10
  for (int i = 0; i < NG; ++i) {
    float w = W2[i * NAB + tid];
    f0 = __fmaf_rn(h0[i], w, f0);
    f1 = __fmaf_rn(h1[i], w, f1);
  }
  e0[tid] = f0;
  e1[tid] = f1;
  __syncthreads();
  if (tid < 64) {
    float4 v;
    v.x = e0[2 * tid]; v.y = e1[2 * tid];
    v.z = e0[2 * tid + 1]; v.w = e1[2 * tid + 1];
    Tp4[(size_t)k * 64 + tid] = v;
  }
}

// ---------------------------------------------------------------------------
// Scatter (src | tl<<16, e_bits) into fixed-capacity bucket slots. (R6 verbatim)
__global__ __launch_bounds__(256)
void bscatter_kernel(const int* __restrict__ a, const float* __restrict__ e,
                     int* __restrict__ bcur, int2* __restrict__ items, int E) {
  int i = blockIdx.x * 256 + threadIdx.x;
  if (i >= 2 * E) return;
  int edge, tgt, src;
  if (i < E) {
    edge = i; src = a[2 * i]; tgt = a[2 * i + 1];
  } else {
    edge = i - E; tgt = a[2 * edge]; src = a[2 * edge + 1];
  }
  int b = tgt >> 7;
  int pos = atomicAdd(&bcur[b * CPAD], 1);
  if (pos < CAP)
    items[(size_t)b * CAP + pos] = make_int2(src | ((tgt & 127) << 16),
                                             __float_as_int(e[edge]));
}

// ---------------------------------------------------------------------------
// Per-bucket counting sort (in LDS) -> items in node order + CSR. (R6 verbatim)
__global__ __launch_bounds__(256)
void local_sort(const int* __restrict__ bcur, int2* __restrict__ items,
                int* __restrict__ nstart, int* __restrict__ nend, int N) {
  __shared__ int2 lit[CAP];
  __shared__ int bin[BN], cur[BN], scn[BN];
  const int b = blockIdx.x;
  const int tid = threadIdx.x;
  const int cnt = min(bcur[b * CPAD], CAP);
  const size_t base = (size_t)b * CAP;

  for (int i = tid; i < cnt; i += 256) lit[i] = items[base + i];
  if (tid < BN) bin[tid] = 0;
  __syncthreads();
  for (int i = tid; i < cnt; i += 256) atomicAdd(&bin[(lit[i].x >> 16) & 127], 1);
  __syncthreads();
  if (tid < BN) scn[tid] = bin[tid];
  __syncthreads();
  for (int d = 1; d < BN; d <<= 1) {
    int v = 0;
    if (tid < BN && tid >= d) v = scn[tid - d];
    __syncthreads();
    if (tid < BN) scn[tid] += v;
    __syncthreads();
  }
  if (tid < BN) {
    int incl = scn[tid];
    int excl = incl - bin[tid];
    cur[tid] = excl;
    int n = b * BN + tid;
    if (n < N) {
      nstart[n] = (int)base + excl;
      nend[n]   = (int)base + incl;
    }
  }
  __syncthreads();
  for (int i = tid; i < cnt; i += 256) {
    int2 it = lit[i];
    int pos = atomicAdd(&cur[(it.x >> 16) & 127], 1);
    items[base + pos] = it;
  }
}

// ---------------------------------------------------------------------------
// Pull: one WAVE per node, register accumulator, no atomics. R6 structure;
// ONLY change: rf read as fp16 (half2 -> float2 convert).
__global__ __launch_bounds__(256)
void pull_kernel(const int* __restrict__ nstart, const int* __restrict__ nend,
                 const int2* __restrict__ items, const __half* __restrict__ rfh,
                 const float4* __restrict__ Tp4, float* __restrict__ agg, int N) {
  const int wv = __builtin_amdgcn_readfirstlane(threadIdx.x >> 6);
  const int n = blockIdx.x * 4 + wv;
  if (n >= N) return;
  const int l = threadIdx.x & 63;
  int j  = nstart[n];
  const int j1 = nend[n];
  const float scale = (float)(TK - 1) / 5.0f;
  float a0 = 0.f, a1 = 0.f;

  for (; j + 4 <= j1; j += 4) {
    int2 p0 = items[j + 0];
    int2 p1 = items[j + 1];
    int2 p2 = items[j + 2];
    int2 p3 = items[j + 3];
    float x0 = __int_as_float(p0.y) * scale; int k0 = min((int)x0, TK - 2); float f0 = x0 - (float)k0;
    float x1 = __int_as_float(p1.y) * scale; int k1 = min((int)x1, TK - 2); float f1 = x1 - (float)k1;
    float x2 = __int_as_float(p2.y) * scale; int k2 = min((int)x2, TK - 2); float f2 = x2 - (float)k2;
    float x3 = __int_as_float(p3.y) * scale; int k3 = min((int)x3, TK - 2); float f3 = x3 - (float)k3;
    float4 t0 = Tp4[(size_t)k0 * 64 + l];
    float4 t1 = Tp4[(size_t)k1 * 64 + l];
    float4 t2 = Tp4[(size_t)k2 * 64 + l];
    float4 t3 = Tp4[(size_t)k3 * 64 + l];
    unsigned q0 = *(const unsigned*)&rfh[((size_t)(p0.x & 0xffff) << 7) + 2 * l];
    unsigned q1 = *(const unsigned*)&rfh[((size_t)(p1.x & 0xffff) << 7) + 2 * l];
    unsigned q2 = *(const unsigned*)&rfh[((size_t)(p2.x & 0xffff) << 7) + 2 * l];
    unsigned q3 = *(const unsigned*)&rfh[((size_t)(p3.x & 0xffff) << 7) + 2 * l];
    float2 r0 = __half22float2(*(const __half2*)&q0);
    float2 r1 = __half22float2(*(const __half2*)&q1);
    float2 r2 = __half22float2(*(const __half2*)&q2);
    float2 r3 = __half22float2(*(const __half2*)&q3);
    a0 = __fmaf_rn(r0.x, __fmaf_rn(f0, t0.y - t0.x, t0.x), a0);
    a1 = __fmaf_rn(r0.y, __fmaf_rn(f0, t0.w - t0.z, t0.z), a1);
    a0 = __fmaf_rn(r1.x, __fmaf_rn(f1, t1.y - t1.x, t1.x), a0);
    a1 = __fmaf_rn(r1.y, __fmaf_rn(f1, t1.w - t1.z, t1.z), a1);
    a0 = __fmaf_rn(r2.x, __fmaf_rn(f2, t2.y - t2.x, t2.x), a0);
    a1 = __fmaf_rn(r2.y, __fmaf_rn(f2, t2.w - t2.z, t2.z), a1);
    a0 = __fmaf_rn(r3.x, __fmaf_rn(f3, t3.y - t3.x, t3.x), a0);
    a1 = __fmaf_rn(r3.y, __fmaf_rn(f3, t3.w - t3.z, t3.z), a1);
  }
  for (; j < j1; ++j) {
    int2 p = items[j];
    float x = __int_as_float(p.y) * scale;
    int k = min((int)x, TK - 2);
    float fr = x - (float)k;
    float4 tv = Tp4[(size_t)k * 64 + l];
    unsigned qq = *(const unsigned*)&rfh[((size_t)(p.x & 0xffff) << 7) + 2 * l];
    float2 rv = __half22float2(*(const __half2*)&qq);
    a0 = __fmaf_rn(rv.x, __fmaf_rn(fr, tv.y - tv.x, tv.x), a0);
    a1 = __fmaf_rn(rv.y, __fmaf_rn(fr, tv.w - tv.z, tv.z), a1);
  }
  float2 o; o.x = a0; o.y = a1;
  *(float2*)&agg[((size_t)n << 7) + 2 * l] = o;
}

// ---------------------------------------------------------------------------
extern "C" void kernel_launch(void* const* d_in, const int* in_sizes, int n_in,
                              void* d_out, int out_size, void* d_ws, size_t ws_size,
                              hipStream_t stream) {
  const float* r     = (const float*)d_in[0];
  const float* e     = (const float*)d_in[1];
  const int*   a     = (const int*)d_in[2];
  const float* W_df1 = (const float*)d_in[3];
  const float* b_df1 = (const float*)d_in[4];
  const float* W_df2 = (const float*)d_in[5];
  const float* b_df2 = (const float*)d_in[6];
  const float* W_af  = (const float*)d_in[7];
  const float* W_d1  = (const float*)d_in[8];
  const float* b_d1  = (const float*)d_in[9];
  const float* W_d2  = (const float*)d_in[10];
  const float* b_d2  = (const float*)d_in[11];

  const int N = in_sizes[0] / NAB;
  const int E = in_sizes[1];
  const int H = 2 * E;
  const int NB = (N + BN - 1) / BN;   // 391 buckets

  // workspace layout (~67 MB). shared region: rf [gemm->cast], then items
  // [scatter->pull], then t1 [step6->7] — strictly sequential lifetimes.
  char* base = (char*)d_ws;
  const size_t shared_bytes = (size_t)NB * CAP * sizeof(int2);   // 27.2 MB
  float*  rf     = (float*)base;                                  // first life
  int2*   items  = (int2*)base;                                   // second life
  float*  t1     = (float*)base;                                  // third life
  float*  agg    = (float*)(base + shared_bytes);                 // N*128 fp32
  __half* rfh    = (__half*)(agg + (size_t)N * NAB);              // N*128 fp16
  float4* Tp4    = (float4*)(rfh + (size_t)N * NAB);              // (TK-1)*64
  int*    bcur   = (int*)(Tp4 + (size_t)(TK - 1) * 64);           // NB*CPAD
  int*    nstart = bcur + NB * CPAD;                              // N
  int*    nend   = nstart + N;                                    // N

  const int gblocks = (N + 31) / 32;
  const int hblocks = (H + 255) / 256;
  const int n4 = N * NAB / 4;

  // 1) fp32 interleaved ef lerp table
  build_tp<<<TK - 1, 128, 0, stream>>>(W_df1, b_df1, W_df2, b_df2, Tp4);
  // 2) rf = r @ W_af (fp32, proven), then cast to fp16
  gemm128<<<gblocks, 128, 0, stream>>>(r, W_af, nullptr, rf, N, 0);
  cast_rf<<<(n4 + 255) / 256, 256, 0, stream>>>((const float4*)rf, (uint2*)rfh, n4);
  // 3) slot-scatter into 128-node buckets (rf region now dead -> items)
  hipMemsetAsync(bcur, 0, (size_t)NB * CPAD * sizeof(int), stream);
  bscatter_kernel<<<hblocks, 256, 0, stream>>>(a, e, bcur, items, E);
  // 4) per-bucket counting sort -> node-ordered items + CSR
  local_sort<<<NB, 256, 0, stream>>>(bcur, items, nstart, nend, N);
  // 5) wave-per-node pull (fp16 rf gathers, fp32 table, register accumulation)
  pull_kernel<<<(N + 3) / 4, 256, 0, stream>>>(nstart, nend, items, rfh, Tp4, agg, N);
  // 6) t1 = ssp(agg @ W_d1 + b_d1)  (items region now dead -> t1)
  gemm128<<<gblocks, 128, 0, stream>>>(agg, W_d1, b_d1, t1, N, 1);
  // 7) out = t1 @ W_d2 + b_d2
  gemm128<<<gblocks, 128, 0, stream>>>(t1, W_d2, b_d2, (float*)d_out, N, 0);
}